// Round 1
// baseline (201.736 us; speedup 1.0000x reference)
//
#include <hip/hip_runtime.h>

// Problem constants (from reference): B=64, C=512, H=W=32, N=1, A=16
#define B_DIM 64
#define C_DIM 512
#define A_DIM 16
#define HW    1024           // H*W
#define EPS   1e-5f

// ---------------------------------------------------------------------------
// Kernel 1: per-(b,c) row reduction of x (contiguous 1024 floats each).
// Writes s1[c*B + b] = sum(x), sq[c*B + b] = sum(x^2) into workspace.
// One block per (b,c); 256 threads, one float4 per thread (fully coalesced).
// ---------------------------------------------------------------------------
__global__ __launch_bounds__(256) void reduce_rows(const float* __restrict__ x,
                                                   float* __restrict__ s1,
                                                   float* __restrict__ sq) {
    const int bc = blockIdx.x;                       // = b*C + c (matches x layout)
    const float4* p = reinterpret_cast<const float4*>(x + (size_t)bc * HW);
    float4 v = p[threadIdx.x];
    float s = v.x + v.y + v.z + v.w;
    float q = v.x * v.x + v.y * v.y + v.z * v.z + v.w * v.w;
#pragma unroll
    for (int off = 32; off > 0; off >>= 1) {
        s += __shfl_down(s, off);
        q += __shfl_down(q, off);
    }
    __shared__ float ls[4], lq[4];
    const int wid = threadIdx.x >> 6;
    const int lane = threadIdx.x & 63;
    if (lane == 0) { ls[wid] = s; lq[wid] = q; }
    __syncthreads();
    if (threadIdx.x == 0) {
        s = ls[0] + ls[1] + ls[2] + ls[3];
        q = lq[0] + lq[1] + lq[2] + lq[3];
        const int b = bc >> 9;                       // bc / C_DIM
        const int c = bc & (C_DIM - 1);
        s1[c * B_DIM + b] = s;                       // [c][b] layout -> coalesced in K2
        sq[c * B_DIM + b] = q;
    }
}

// ---------------------------------------------------------------------------
// Kernel 2: blocks [0,512): per-channel batch stats + new_x.
//           blocks [512,528): LayerNorm of router_weights^T rows -> wn_t[c][a].
// 64 threads = 1 wave per block.
// ---------------------------------------------------------------------------
__global__ __launch_bounds__(64) void stats_newx_ln(
    const float* __restrict__ s1, const float* __restrict__ sq,
    const float* __restrict__ bn_g, const float* __restrict__ bn_b,
    const float* __restrict__ rw, const float* __restrict__ ln_g,
    const float* __restrict__ ln_b,
    float* __restrict__ newx, float* __restrict__ wn_t) {
    const int lane = threadIdx.x;
    if (blockIdx.x < C_DIM) {
        // --- batch-norm stats for channel c + pooled new_x ---
        const int c = blockIdx.x;
        const float s = s1[c * B_DIM + lane];        // lane == b
        const float q = sq[c * B_DIM + lane];
        float ts = s, tq = q;
#pragma unroll
        for (int off = 32; off > 0; off >>= 1) {
            ts += __shfl_down(ts, off);
            tq += __shfl_down(tq, off);
        }
        const float mu  = __shfl(ts, 0) * (1.0f / 65536.0f);   // /(B*H*W)
        const float var = __shfl(tq, 0) * (1.0f / 65536.0f) - mu * mu;
        const float r   = rsqrtf(var + EPS);
        const float nx  = bn_g[c] * (s * (1.0f / 1024.0f) - mu) * r + bn_b[c];
        newx[lane * C_DIM + c] = nx;                 // new_x[b][c]
    } else {
        // --- LayerNorm over C of router_weights[:,a] (i.e. W^T row a) ---
        const int a = blockIdx.x - C_DIM;
        float wv[8];
        float s = 0.f, q = 0.f;
#pragma unroll
        for (int j = 0; j < 8; j++) {
            const int c = j * 64 + lane;
            wv[j] = rw[c * A_DIM + a];
            s += wv[j];
            q += wv[j] * wv[j];
        }
#pragma unroll
        for (int off = 32; off > 0; off >>= 1) {
            s += __shfl_down(s, off);
            q += __shfl_down(q, off);
        }
        const float m = __shfl(s, 0) * (1.0f / 512.0f);
        const float v = __shfl(q, 0) * (1.0f / 512.0f) - m * m;
        const float r = rsqrtf(v + EPS);
#pragma unroll
        for (int j = 0; j < 8; j++) {
            const int c = j * 64 + lane;
            wn_t[c * A_DIM + a] = (wv[j] - m) * r * ln_g[c] + ln_b[c];  // [c][a]
        }
    }
}

// ---------------------------------------------------------------------------
// Kernel 3: logits[b][a] = new_x[b,:] . wn[:,a] + bias[a]; softmax over a.
// One block per b; 64 lanes: lane = a + 16*chunk, each lane does 128 MACs,
// combine chunks via shfl_xor(16|32), softmax within 16-lane subgroups.
// ---------------------------------------------------------------------------
__global__ __launch_bounds__(64) void matmul_softmax(
    const float* __restrict__ newx, const float* __restrict__ wn_t,
    const float* __restrict__ rbias,
    float* __restrict__ logits, float* __restrict__ probs) {
    const int b = blockIdx.x;
    const int lane = threadIdx.x;
    const int a = lane & 15;
    const int chunk = lane >> 4;
    const float* xr = newx + b * C_DIM + chunk * 128;
    const float* wr = wn_t + (chunk * 128) * A_DIM + a;
    float acc = 0.f;
#pragma unroll 8
    for (int i = 0; i < 128; i++) {
        acc += xr[i] * wr[i * A_DIM];
    }
    acc += __shfl_xor(acc, 16);
    acc += __shfl_xor(acc, 32);
    const float logit = acc + rbias[a];
    float mx = logit;
#pragma unroll
    for (int m = 1; m < 16; m <<= 1) mx = fmaxf(mx, __shfl_xor(mx, m));
    const float e = expf(logit - mx);
    float se = e;
#pragma unroll
    for (int m = 1; m < 16; m <<= 1) se += __shfl_xor(se, m);
    const float prob = e / se;
    if (lane < 16) {                                 // lane == a here
        logits[b * A_DIM + lane] = logit;
        probs[b * A_DIM + lane] = prob;
    }
}

extern "C" void kernel_launch(void* const* d_in, const int* in_sizes, int n_in,
                              void* d_out, int out_size, void* d_ws, size_t ws_size,
                              hipStream_t stream) {
    const float* x     = (const float*)d_in[0];   // [B,C,H,W]
    const float* rw    = (const float*)d_in[1];   // [1,C,A]
    const float* rbias = (const float*)d_in[2];   // [1,A]
    const float* bn_g  = (const float*)d_in[3];   // [1,C]
    const float* bn_b  = (const float*)d_in[4];
    const float* ln_g  = (const float*)d_in[5];
    const float* ln_b  = (const float*)d_in[6];

    float* out    = (float*)d_out;
    float* newx   = out;                          // 32768 floats: new_x [1,64,512]
    float* logits = out + B_DIM * C_DIM;          // 1024 floats
    float* probs  = logits + B_DIM * A_DIM;       // 1024 floats

    float* s1   = (float*)d_ws;                   // 32768 floats  [c][b]
    float* sq   = s1 + B_DIM * C_DIM;             // 32768 floats  [c][b]
    float* wn_t = sq + B_DIM * C_DIM;             // 8192 floats   [c][a]

    reduce_rows<<<B_DIM * C_DIM, 256, 0, stream>>>(x, s1, sq);
    stats_newx_ln<<<C_DIM + A_DIM, 64, 0, stream>>>(s1, sq, bn_g, bn_b, rw,
                                                    ln_g, ln_b, newx, wn_t);
    matmul_softmax<<<B_DIM, 64, 0, stream>>>(newx, wn_t, rbias, logits, probs);
}